// Round 10
// baseline (313.100 us; speedup 1.0000x reference)
//
#include <hip/hip_runtime.h>
#include <hip/hip_bf16.h>
#include <math.h>

namespace {
constexpr int kD = 256;      // embed dim
constexpr int kDOUT = 256;   // out dim
constexpr int kNQ = 65536;   // num query nodes
constexpr int kE = 262144;   // edges
constexpr float kAlpha = 0.2f;
constexpr float kEps = 1e-12f;
}

typedef short bf16x8 __attribute__((ext_vector_type(8)));
typedef float f32x4 __attribute__((ext_vector_type(4)));
typedef unsigned short u16x8 __attribute__((ext_vector_type(8)));

static __device__ __forceinline__ float bf2f(unsigned short u) {
  union { unsigned int i; float f; } v;
  v.i = ((unsigned int)u) << 16;
  return v.f;
}

// c[j] = sum_k a[k][j] * a2[k]   (a is (DOUT, 2D) row-major; j in [0, 512))
__global__ void compute_c_kernel(const float* __restrict__ a,
                                 const float* __restrict__ a2,
                                 float* __restrict__ c) {
  const int j = blockIdx.x * blockDim.x + threadIdx.x;  // 0..511
  float s = 0.f;
#pragma unroll 8
  for (int k = 0; k < kDOUT; ++k) s = fmaf(a[k * (2 * kD) + j], a2[k], s);
  c[j] = s;
}

// zero count[NQ]
__global__ void zero_kernel(int4* __restrict__ p) {
  p[blockIdx.x * 256 + threadIdx.x] = int4{0, 0, 0, 0};
}

// trans (256x256 f32) -> bf16
__global__ void cvt_trans_kernel(const float* __restrict__ t, ushort* __restrict__ tb) {
  const int i = blockIdx.x * 256 + threadIdx.x;  // 4 elems each
  const float4 v = reinterpret_cast<const float4*>(t)[i];
  union { ushort4 u; __hip_bfloat16 h[4]; } p;
  p.h[0] = __float2bfloat16(v.x);
  p.h[1] = __float2bfloat16(v.y);
  p.h[2] = __float2bfloat16(v.z);
  p.h[3] = __float2bfloat16(v.w);
  reinterpret_cast<ushort4*>(tb)[i] = p.u;
}

// histogram of query_list into count[]
__global__ __launch_bounds__(256) void hist_kernel(const int* __restrict__ query_list,
                                                   int* __restrict__ count) {
  const int i = blockIdx.x * 256 + threadIdx.x;
  const int4 q = reinterpret_cast<const int4*>(query_list)[i];
  atomicAdd(&count[q.x], 1);
  atomicAdd(&count[q.y], 1);
  atomicAdd(&count[q.z], 1);
  atomicAdd(&count[q.w], 1);
}

// Single-block exclusive scan of count[NQ] -> offsets, cursor copy.
__global__ __launch_bounds__(1024) void scan_kernel(const int* __restrict__ count,
                                                    int* __restrict__ offsets,
                                                    int* __restrict__ cursor) {
  __shared__ int partial[1024];
  const int t = threadIdx.x;
  int4 loc[16];
#pragma unroll
  for (int i = 0; i < 16; ++i) loc[i] = reinterpret_cast<const int4*>(count)[t * 16 + i];
  int s = 0;
#pragma unroll
  for (int i = 0; i < 16; ++i) s += loc[i].x + loc[i].y + loc[i].z + loc[i].w;
  partial[t] = s;
  __syncthreads();
  for (int off = 1; off < 1024; off <<= 1) {
    int v = (t >= off) ? partial[t - off] : 0;
    __syncthreads();
    partial[t] += v;
    __syncthreads();
  }
  int run = partial[t] - s;
#pragma unroll
  for (int i = 0; i < 16; ++i) {
    const int4 v = loc[i];
    int4 o;
    o.x = run; run += v.x;
    o.y = run; run += v.y;
    o.z = run; run += v.z;
    o.w = run; run += v.w;
    reinterpret_cast<int4*>(offsets)[t * 16 + i] = o;
    reinterpret_cast<int4*>(cursor)[t * 16 + i] = o;
  }
  if (t == 1023) offsets[kNQ] = run;  // == E
}

// Pass 1: streaming sweep, 4 edges per wave (16 lanes each, 8 independent
// 16B loads per lane in flight). ev = exp(-leaky(key.ck + query.cq));
// write bf16(ev*key_row) in EDGE order; fused CSR scatter on group-lane 0.
__global__ __launch_bounds__(256) void edge_stream_kernel(
    const float* __restrict__ key_embed,
    const float* __restrict__ query_embed,
    const int* __restrict__ qlist,
    const float* __restrict__ c,
    int* __restrict__ cursor,
    int* __restrict__ edge_ids,
    ushort* __restrict__ wkey,
    float* __restrict__ e_out) {
  const int wid = threadIdx.x >> 6;
  const int lane = threadIdx.x & 63;
  const int g = lane >> 4;
  const int l4 = lane & 15;
  const int edge = blockIdx.x * 16 + wid * 4 + g;

  const float4* krow = reinterpret_cast<const float4*>(key_embed) + (size_t)edge * 64 + l4 * 4;
  const float4* qrow = reinterpret_cast<const float4*>(query_embed) + (size_t)edge * 64 + l4 * 4;
  float4 k4[4], q4[4];
#pragma unroll
  for (int t = 0; t < 4; ++t) k4[t] = krow[t];
#pragma unroll
  for (int t = 0; t < 4; ++t) q4[t] = qrow[t];

  float4 ck[4], cq[4];
#pragma unroll
  for (int t = 0; t < 4; ++t) {
    ck[t] = reinterpret_cast<const float4*>(c)[l4 * 4 + t];
    cq[t] = reinterpret_cast<const float4*>(c)[64 + l4 * 4 + t];
  }

  float s = 0.f;
#pragma unroll
  for (int t = 0; t < 4; ++t) {
    s += k4[t].x * ck[t].x + k4[t].y * ck[t].y + k4[t].z * ck[t].z + k4[t].w * ck[t].w;
    s += q4[t].x * cq[t].x + q4[t].y * cq[t].y + q4[t].z * cq[t].z + q4[t].w * cq[t].w;
  }
#pragma unroll
  for (int off = 1; off < 16; off <<= 1) s += __shfl_xor(s, off, 64);

  const float p = (s > 0.f) ? s : kAlpha * s;   // leaky_relu
  const float ev = __expf(-p);

  ushort* orow = wkey + (size_t)edge * kD + l4 * 16;
#pragma unroll
  for (int half = 0; half < 2; ++half) {
    const float4 a = k4[half * 2], b = k4[half * 2 + 1];
    union { u16x8 u; __hip_bfloat16 h[8]; } pk;
    pk.h[0] = __float2bfloat16(ev * a.x);
    pk.h[1] = __float2bfloat16(ev * a.y);
    pk.h[2] = __float2bfloat16(ev * a.z);
    pk.h[3] = __float2bfloat16(ev * a.w);
    pk.h[4] = __float2bfloat16(ev * b.x);
    pk.h[5] = __float2bfloat16(ev * b.y);
    pk.h[6] = __float2bfloat16(ev * b.z);
    pk.h[7] = __float2bfloat16(ev * b.w);
    *reinterpret_cast<u16x8*>(orow + half * 8) = pk.u;
  }

  if (l4 == 0) {
    e_out[edge] = ev;
    const int q = qlist[edge];
    const int pos = atomicAdd(&cursor[q], 1);
    edge_ids[pos] = edge;
  }
}

// Pass 2: 4 queries per wave, 16 lanes per query (2 x u16x8 = 32B per lane
// per row; a degree-4 query issues 8 independent loads at once).
// rs replicated in-group (no reduce); coalesced 32B/lane write.
__global__ __launch_bounds__(256) void gather_kernel(
    const ushort* __restrict__ wkey,
    const float* __restrict__ e,
    const int* __restrict__ offsets,
    const int* __restrict__ edge_ids,
    ushort* __restrict__ accb) {
  const int wid = threadIdx.x >> 6;
  const int lane = threadIdx.x & 63;
  const int g = lane >> 4;
  const int l4 = lane & 15;
  const int q = blockIdx.x * 16 + wid * 4 + g;
  const int s0 = offsets[q], s1 = offsets[q + 1];

  float acc[16] = {};
  float rs = 0.f;

  for (int base = s0; base < s1; base += 16) {
    const int m = min(16, s1 - base);
    const int eid = (l4 < m) ? edge_ids[base + l4] : 0;
    const float evl = (l4 < m) ? e[eid] : 0.f;
    for (int i = 0; i < m; i += 4) {
      const int kc = min(4, m - i);
      u16x8 u[4][2];
      float evv[4];
#pragma unroll
      for (int t = 0; t < 4; ++t) {
        if (t < kc) {
          const int eg = __shfl(eid, (g << 4) + i + t, 64);
          const ushort* row = wkey + (size_t)eg * kD + l4 * 16;
          u[t][0] = *reinterpret_cast<const u16x8*>(row);
          u[t][1] = *reinterpret_cast<const u16x8*>(row + 8);
          evv[t] = __shfl(evl, (g << 4) + i + t, 64);
        }
      }
#pragma unroll
      for (int t = 0; t < 4; ++t) {
        if (t < kc) {
#pragma unroll
          for (int j = 0; j < 8; ++j) acc[j] += bf2f((unsigned short)u[t][0][j]);
#pragma unroll
          for (int j = 0; j < 8; ++j) acc[8 + j] += bf2f((unsigned short)u[t][1][j]);
          rs += evv[t];
        }
      }
    }
  }

  const float inv = 1.0f / ((rs == 0.f) ? kEps : rs);
  union { u16x8 u; __hip_bfloat16 h[8]; } p0, p1;
#pragma unroll
  for (int j = 0; j < 8; ++j) p0.h[j] = __float2bfloat16(acc[j] * inv);
#pragma unroll
  for (int j = 0; j < 8; ++j) p1.h[j] = __float2bfloat16(acc[8 + j] * inv);
  ushort* orow = accb + (size_t)q * kD + l4 * 16;
  *reinterpret_cast<u16x8*>(orow) = p0.u;
  *reinterpret_cast<u16x8*>(orow + 8) = p1.u;
}

// out = elu(A @ B^T).  A: (NQ,256) bf16 row-major (pre-normalized), B = trans bf16.
// One wave per 16-row strip, full N=256 in registers (16 n-tiles of 16x16x32 MFMA).
__global__ __launch_bounds__(256) void out_gemm_mfma_kernel(
    const ushort* __restrict__ A,
    const ushort* __restrict__ B,
    float* __restrict__ out) {
  const int wid = threadIdx.x >> 6;
  const int lane = threadIdx.x & 63;
  const int row0 = (blockIdx.x * 4 + wid) * 16;
  const int m = lane & 15;
  const int kb = (lane >> 4) * 8;

  f32x4 acc[16] = {};

  for (int kt = 0; kt < kD; kt += 32) {
    const bf16x8 af = *reinterpret_cast<const bf16x8*>(&A[(size_t)(row0 + m) * kD + kt + kb]);
#pragma unroll
    for (int nt = 0; nt < 16; ++nt) {
      const bf16x8 bf = *reinterpret_cast<const bf16x8*>(&B[(size_t)(nt * 16 + m) * kD + kt + kb]);
      acc[nt] = __builtin_amdgcn_mfma_f32_16x16x32_bf16(af, bf, acc[nt], 0, 0, 0);
    }
  }

#pragma unroll
  for (int nt = 0; nt < 16; ++nt) {
#pragma unroll
    for (int r = 0; r < 4; ++r) {
      const int row = row0 + (lane >> 4) * 4 + r;
      const int col = nt * 16 + (lane & 15);
      const float x = acc[nt][r];
      out[(size_t)row * kDOUT + col] = (x > 0.f) ? x : expm1f(x);
    }
  }
}

extern "C" void kernel_launch(void* const* d_in, const int* in_sizes, int n_in,
                              void* d_out, int out_size, void* d_ws, size_t ws_size,
                              hipStream_t stream) {
  // inputs: 0 key_list(int,E) [unused], 1 key_embed(f32,E*256), 2 query_list(int,E),
  //         3 query_embed(f32,E*256), 4 a(f32,256*512), 5 a_2(f32,256), 6 trans(f32,256*256)
  const float* key_embed = (const float*)d_in[1];
  const int* query_list = (const int*)d_in[2];
  const float* query_embed = (const float*)d_in[3];
  const float* a = (const float*)d_in[4];
  const float* a2 = (const float*)d_in[5];
  const float* trans = (const float*)d_in[6];
  float* out = (float*)d_out;

  // workspace (float units, 16B-aligned):
  // c[512] | count[NQ] | offsets[NQ+4] | cursor[NQ] | edge_ids[E] | e[E]
  // | wkey[E*256 ushort] | accb[NQ*256 ushort] | transb[256*256 ushort]
  float* ws = (float*)d_ws;
  float* c = ws;
  int* count = (int*)(ws + 512);
  int* offsets = count + kNQ;
  int* cursor = offsets + kNQ + 4;
  int* edge_ids = cursor + kNQ;
  float* e = (float*)(edge_ids + kE);
  ushort* wkey = (ushort*)(e + kE);                               // kE*256 bf16
  ushort* accb = wkey + (size_t)kE * kD;                          // kNQ*256 bf16
  ushort* transb = accb + (size_t)kNQ * kD;                       // 256*256 bf16

  zero_kernel<<<kNQ / 4 / 256, 256, 0, stream>>>((int4*)count);
  compute_c_kernel<<<2, 256, 0, stream>>>(a, a2, c);
  cvt_trans_kernel<<<kDOUT * kD / 4 / 256, 256, 0, stream>>>(trans, transb);
  hist_kernel<<<kE / 4 / 256, 256, 0, stream>>>(query_list, count);
  scan_kernel<<<1, 1024, 0, stream>>>(count, offsets, cursor);
  edge_stream_kernel<<<kE / 16, 256, 0, stream>>>(key_embed, query_embed, query_list, c,
                                                  cursor, edge_ids, wkey, e);
  gather_kernel<<<kNQ / 16, 256, 0, stream>>>(wkey, e, offsets, edge_ids, accb);
  out_gemm_mfma_kernel<<<kNQ / 64, 256, 0, stream>>>(accb, transb, out);
}

// Round 11
// 277.330 us; speedup vs baseline: 1.1290x; 1.1290x over previous
//
#include <hip/hip_runtime.h>
#include <hip/hip_bf16.h>
#include <math.h>

namespace {
constexpr int kD = 256;      // embed dim
constexpr int kDOUT = 256;   // out dim
constexpr int kNQ = 65536;   // num query nodes
constexpr int kE = 262144;   // edges
constexpr float kAlpha = 0.2f;
constexpr float kEps = 1e-12f;
constexpr int kCap = 16;     // slots per query (P(deg>16) ~ 1e-6 per query)
constexpr int kOvfMax = 4096;
}

typedef short bf16x8 __attribute__((ext_vector_type(8)));
typedef float f32x4 __attribute__((ext_vector_type(4)));
typedef unsigned short u16x8 __attribute__((ext_vector_type(8)));

static __device__ __forceinline__ float bf2f(unsigned short u) {
  union { unsigned int i; float f; } v;
  v.i = ((unsigned int)u) << 16;
  return v.f;
}

// c[j] = sum_k a[k][j] * a2[k]   (a is (DOUT, 2D) row-major; j in [0, 512))
__global__ void compute_c_kernel(const float* __restrict__ a,
                                 const float* __restrict__ a2,
                                 float* __restrict__ c) {
  const int j = blockIdx.x * blockDim.x + threadIdx.x;  // 0..511
  float s = 0.f;
#pragma unroll 8
  for (int k = 0; k < kDOUT; ++k) s = fmaf(a[k * (2 * kD) + j], a2[k], s);
  c[j] = s;
}

// zero count[NQ] (ints) + rowsum[NQ] (floats) + ovf_n
__global__ void zero_kernel(int4* __restrict__ p, int* __restrict__ ovf_n) {
  p[blockIdx.x * 256 + threadIdx.x] = int4{0, 0, 0, 0};
  if (blockIdx.x == 0 && threadIdx.x == 0) *ovf_n = 0;
}

// trans (256x256 f32) -> bf16
__global__ void cvt_trans_kernel(const float* __restrict__ t, ushort* __restrict__ tb) {
  const int i = blockIdx.x * 256 + threadIdx.x;  // 4 elems each
  const float4 v = reinterpret_cast<const float4*>(t)[i];
  union { ushort4 u; __hip_bfloat16 h[4]; } p;
  p.h[0] = __float2bfloat16(v.x);
  p.h[1] = __float2bfloat16(v.y);
  p.h[2] = __float2bfloat16(v.z);
  p.h[3] = __float2bfloat16(v.w);
  reinterpret_cast<ushort4*>(tb)[i] = p.u;
}

// Single pass over edges: 2 edges per wave (32 lanes each; 4 independent 16B
// loads/lane). ev = exp(-leaky(key.ck + query.cq)); slot = count[q]++;
// rowsum[q] += ev; write bf16(ev*key_row) to wkey[q*16+slot] (capacity bin,
// random posted 512B write). Overflow (slot>=16) goes to a tiny list.
__global__ __launch_bounds__(256) void sweep_kernel(
    const float* __restrict__ key_embed,
    const float* __restrict__ query_embed,
    const int* __restrict__ qlist,
    const float* __restrict__ c,
    int* __restrict__ count,
    float* __restrict__ rowsum,
    int* __restrict__ ovf_n,
    int* __restrict__ ovf_q,
    ushort* __restrict__ wovf,
    ushort* __restrict__ wkey) {
  const int wid = threadIdx.x >> 6;
  const int lane = threadIdx.x & 63;
  const int g = lane >> 5;        // edge sub-slot in wave
  const int l5 = lane & 31;       // lane within 32-group; covers floats [l5*8, +8)
  const int edge = blockIdx.x * 8 + wid * 2 + g;

  const float4* kr = reinterpret_cast<const float4*>(key_embed) + (size_t)edge * 64 + l5 * 2;
  const float4* qr = reinterpret_cast<const float4*>(query_embed) + (size_t)edge * 64 + l5 * 2;
  const float4 k0 = kr[0], k1 = kr[1];
  const float4 q0 = qr[0], q1 = qr[1];
  const float4 c0 = reinterpret_cast<const float4*>(c)[l5 * 2];
  const float4 c1 = reinterpret_cast<const float4*>(c)[l5 * 2 + 1];
  const float4 d0 = reinterpret_cast<const float4*>(c)[64 + l5 * 2];
  const float4 d1 = reinterpret_cast<const float4*>(c)[64 + l5 * 2 + 1];

  float s = k0.x * c0.x + k0.y * c0.y + k0.z * c0.z + k0.w * c0.w
          + k1.x * c1.x + k1.y * c1.y + k1.z * c1.z + k1.w * c1.w
          + q0.x * d0.x + q0.y * d0.y + q0.z * d0.z + q0.w * d0.w
          + q1.x * d1.x + q1.y * d1.y + q1.z * d1.z + q1.w * d1.w;
#pragma unroll
  for (int off = 1; off < 32; off <<= 1) s += __shfl_xor(s, off, 64);

  const float p = (s > 0.f) ? s : kAlpha * s;   // leaky_relu
  const float ev = __expf(-p);

  int q = 0, slot = 0;
  if (l5 == 0) {
    q = qlist[edge];
    slot = atomicAdd(&count[q], 1);
    unsafeAtomicAdd(&rowsum[q], ev);
  }
  q = __shfl(q, g * 32, 64);
  slot = __shfl(slot, g * 32, 64);

  union { u16x8 u; __hip_bfloat16 h[8]; } pk;
  pk.h[0] = __float2bfloat16(ev * k0.x);
  pk.h[1] = __float2bfloat16(ev * k0.y);
  pk.h[2] = __float2bfloat16(ev * k0.z);
  pk.h[3] = __float2bfloat16(ev * k0.w);
  pk.h[4] = __float2bfloat16(ev * k1.x);
  pk.h[5] = __float2bfloat16(ev * k1.y);
  pk.h[6] = __float2bfloat16(ev * k1.z);
  pk.h[7] = __float2bfloat16(ev * k1.w);

  if (slot < kCap) {
    *reinterpret_cast<u16x8*>(wkey + ((size_t)q * kCap + slot) * kD + l5 * 8) = pk.u;
  } else {
    int o = 0;
    if (l5 == 0) {
      o = atomicAdd(ovf_n, 1);
      if (o < kOvfMax) ovf_q[o] = q;
    }
    o = __shfl(o, g * 32, 64);
    if (o < kOvfMax)
      *reinterpret_cast<u16x8*>(wovf + (size_t)o * kD + l5 * 8) = pk.u;
  }
}

// Gather: 2 queries per wave (32 lanes each). Reads the query's CONTIGUOUS
// capacity-bin rows (deg x 512B, ~2KB granule), 4 rows unrolled/in-flight;
// adds rare overflow entries; normalizes by rowsum; coalesced bf16 write.
__global__ __launch_bounds__(256) void gather_kernel(
    const ushort* __restrict__ wkey,
    const ushort* __restrict__ wovf,
    const int* __restrict__ ovf_q,
    const int* __restrict__ ovf_n,
    const int* __restrict__ count,
    const float* __restrict__ rowsum,
    ushort* __restrict__ accb) {
  const int wid = threadIdx.x >> 6;
  const int lane = threadIdx.x & 63;
  const int g = lane >> 5;
  const int l5 = lane & 31;
  const int q = blockIdx.x * 8 + wid * 2 + g;

  const int cnt = count[q];
  const int cm = min(cnt, kCap);
  const ushort* base = wkey + (size_t)q * kCap * kD + l5 * 8;

  float acc[8] = {};
  int r = 0;
  for (; r + 4 <= cm; r += 4) {
    const u16x8 u0 = *reinterpret_cast<const u16x8*>(base + (size_t)(r + 0) * kD);
    const u16x8 u1 = *reinterpret_cast<const u16x8*>(base + (size_t)(r + 1) * kD);
    const u16x8 u2 = *reinterpret_cast<const u16x8*>(base + (size_t)(r + 2) * kD);
    const u16x8 u3 = *reinterpret_cast<const u16x8*>(base + (size_t)(r + 3) * kD);
#pragma unroll
    for (int j = 0; j < 8; ++j)
      acc[j] += (bf2f((unsigned short)u0[j]) + bf2f((unsigned short)u1[j])) +
                (bf2f((unsigned short)u2[j]) + bf2f((unsigned short)u3[j]));
  }
  for (; r < cm; ++r) {
    const u16x8 u = *reinterpret_cast<const u16x8*>(base + (size_t)r * kD);
#pragma unroll
    for (int j = 0; j < 8; ++j) acc[j] += bf2f((unsigned short)u[j]);
  }

  if (cnt > kCap) {   // rare: scan the tiny overflow list
    const int n = min(*ovf_n, kOvfMax);
    for (int i = 0; i < n; ++i) {
      if (ovf_q[i] == q) {
        const u16x8 u = *reinterpret_cast<const u16x8*>(wovf + (size_t)i * kD + l5 * 8);
#pragma unroll
        for (int j = 0; j < 8; ++j) acc[j] += bf2f((unsigned short)u[j]);
      }
    }
  }

  const float rs = rowsum[q];
  const float inv = 1.0f / ((rs == 0.f) ? kEps : rs);
  union { u16x8 u; __hip_bfloat16 h[8]; } pk;
#pragma unroll
  for (int j = 0; j < 8; ++j) pk.h[j] = __float2bfloat16(acc[j] * inv);
  *reinterpret_cast<u16x8*>(accb + (size_t)q * kD + l5 * 8) = pk.u;
}

// out = elu(A @ B^T).  A: (NQ,256) bf16 row-major (pre-normalized), B = trans bf16.
// One wave per 16-row strip, full N=256 in registers (16 n-tiles of 16x16x32 MFMA).
__global__ __launch_bounds__(256) void out_gemm_mfma_kernel(
    const ushort* __restrict__ A,
    const ushort* __restrict__ B,
    float* __restrict__ out) {
  const int wid = threadIdx.x >> 6;
  const int lane = threadIdx.x & 63;
  const int row0 = (blockIdx.x * 4 + wid) * 16;
  const int m = lane & 15;
  const int kb = (lane >> 4) * 8;

  f32x4 acc[16] = {};

  for (int kt = 0; kt < kD; kt += 32) {
    const bf16x8 af = *reinterpret_cast<const bf16x8*>(&A[(size_t)(row0 + m) * kD + kt + kb]);
#pragma unroll
    for (int nt = 0; nt < 16; ++nt) {
      const bf16x8 bf = *reinterpret_cast<const bf16x8*>(&B[(size_t)(nt * 16 + m) * kD + kt + kb]);
      acc[nt] = __builtin_amdgcn_mfma_f32_16x16x32_bf16(af, bf, acc[nt], 0, 0, 0);
    }
  }

#pragma unroll
  for (int nt = 0; nt < 16; ++nt) {
#pragma unroll
    for (int r = 0; r < 4; ++r) {
      const int row = row0 + (lane >> 4) * 4 + r;
      const int col = nt * 16 + (lane & 15);
      const float x = acc[nt][r];
      out[(size_t)row * kDOUT + col] = (x > 0.f) ? x : expm1f(x);
    }
  }
}

extern "C" void kernel_launch(void* const* d_in, const int* in_sizes, int n_in,
                              void* d_out, int out_size, void* d_ws, size_t ws_size,
                              hipStream_t stream) {
  // inputs: 0 key_list(int,E) [unused], 1 key_embed(f32,E*256), 2 query_list(int,E),
  //         3 query_embed(f32,E*256), 4 a(f32,256*512), 5 a_2(f32,256), 6 trans(f32,256*256)
  const float* key_embed = (const float*)d_in[1];
  const int* query_list = (const int*)d_in[2];
  const float* query_embed = (const float*)d_in[3];
  const float* a = (const float*)d_in[4];
  const float* a2 = (const float*)d_in[5];
  const float* trans = (const float*)d_in[6];
  float* out = (float*)d_out;

  // workspace layout (ushort units from base; wkey first for alignment):
  // wkey[NQ*16*256 us = 512MB] | accb[NQ*256 us] | transb[256*256 us]
  // | wovf[kOvfMax*256 us] | c[512 f] | count[NQ i] | rowsum[NQ f] | ovf_n[4 i] | ovf_q[kOvfMax i]
  ushort* wkey = (ushort*)d_ws;
  ushort* accb = wkey + (size_t)kNQ * kCap * kD;
  ushort* transb = accb + (size_t)kNQ * kD;
  ushort* wovf = transb + (size_t)kDOUT * kD;
  float* c = (float*)(wovf + (size_t)kOvfMax * kD);
  int* count = (int*)(c + 512);
  float* rowsum = (float*)(count + kNQ);
  int* ovf_n = (int*)(rowsum + kNQ);
  int* ovf_q = ovf_n + 4;

  // zero count + rowsum (contiguous, 2*kNQ ints) + ovf_n
  zero_kernel<<<2 * kNQ / 4 / 256, 256, 0, stream>>>((int4*)count, ovf_n);
  compute_c_kernel<<<2, 256, 0, stream>>>(a, a2, c);
  cvt_trans_kernel<<<kDOUT * kD / 4 / 256, 256, 0, stream>>>(trans, transb);
  sweep_kernel<<<kE / 8, 256, 0, stream>>>(key_embed, query_embed, query_list, c,
                                           count, rowsum, ovf_n, ovf_q, wovf, wkey);
  gather_kernel<<<kNQ / 8, 256, 0, stream>>>(wkey, wovf, ovf_q, ovf_n, count, rowsum, accb);
  out_gemm_mfma_kernel<<<kNQ / 64, 256, 0, stream>>>(accb, transb, out);
}